// Round 1
// baseline (4603.639 us; speedup 1.0000x reference)
//
#include <hip/hip_runtime.h>
#include <math.h>

#define HID   1024
#define NEXP  8
#define INTER 2816
#define NTOK  16384
#define CAP   2048
#define EPSF  1e-5f

#define BM 64
#define BN 64
#define BK 16
#define LDST 68   // padded LDS row stride (floats); 272B = 17*16B keeps float4 alignment

// ---------------- wave helpers ----------------
__device__ __forceinline__ float waveSum(float v) {
#pragma unroll
    for (int o = 32; o > 0; o >>= 1) v += __shfl_down(v, o);
    return v;
}
__device__ __forceinline__ float waveMax(float v) {
#pragma unroll
    for (int o = 32; o > 0; o >>= 1) v = fmaxf(v, __shfl_down(v, o));
    return v;
}

// ---------------- 1. LayerNorm + router logits + aux(lse^2) ----------------
// one block (256 thr) per token; thread t handles h = 4t..4t+3
__global__ __launch_bounds__(256) void k_ln_router(
    const float* __restrict__ x, const float* __restrict__ gamma,
    const float* __restrict__ beta, const float* __restrict__ gw,
    float* __restrict__ logits, float* __restrict__ aux)
{
    const int n   = blockIdx.x;
    const int tid = threadIdx.x;
    const int wid = tid >> 6, lane = tid & 63;

    const float4 xv = *(const float4*)(x + (size_t)n * HID + tid * 4);
    float s  = xv.x + xv.y + xv.z + xv.w;
    float ss = xv.x*xv.x + xv.y*xv.y + xv.z*xv.z + xv.w*xv.w;
    s  = waveSum(s);
    ss = waveSum(ss);

    __shared__ float rs_[4], rss_[4];
    __shared__ float mu_s, rstd_s;
    if (lane == 0) { rs_[wid] = s; rss_[wid] = ss; }
    __syncthreads();
    if (tid == 0) {
        float S  = rs_[0] + rs_[1] + rs_[2] + rs_[3];
        float SS = rss_[0] + rss_[1] + rss_[2] + rss_[3];
        float mu  = S / (float)HID;
        float var = SS / (float)HID - mu * mu;
        mu_s = mu; rstd_s = rsqrtf(var + EPSF);
    }
    __syncthreads();
    const float mu = mu_s, rstd = rstd_s;

    const float4 g = *(const float4*)(gamma + tid * 4);
    const float4 b = *(const float4*)(beta  + tid * 4);
    float xn[4];
    xn[0] = (xv.x - mu) * rstd * g.x + b.x;
    xn[1] = (xv.y - mu) * rstd * g.y + b.y;
    xn[2] = (xv.z - mu) * rstd * g.z + b.z;
    xn[3] = (xv.w - mu) * rstd * g.w + b.w;

    float pl[NEXP];
#pragma unroll
    for (int e = 0; e < NEXP; ++e) {
        const float4 w = *(const float4*)(gw + (size_t)e * HID + tid * 4);
        pl[e] = xn[0]*w.x + xn[1]*w.y + xn[2]*w.z + xn[3]*w.w;
    }

    __shared__ float red[4][NEXP];
#pragma unroll
    for (int e = 0; e < NEXP; ++e) {
        float v = waveSum(pl[e]);
        if (lane == 0) red[wid][e] = v;
    }
    __syncthreads();
    __shared__ float lrow[NEXP];
    if (tid < NEXP) {
        float v = red[0][tid] + red[1][tid] + red[2][tid] + red[3][tid];
        logits[(size_t)n * NEXP + tid] = v;
        lrow[tid] = v;
    }
    __syncthreads();
    if (tid == 0) {
        float m = lrow[0];
#pragma unroll
        for (int e = 1; e < NEXP; ++e) m = fmaxf(m, lrow[e]);
        float se = 0.f;
#pragma unroll
        for (int e = 0; e < NEXP; ++e) se += expf(lrow[e] - m);
        float lse = m + logf(se);
        atomicAdd(aux, lse * lse);
    }
}

// ---------------- 2. per-expert column max & softmax denom (over tokens) ----------------
__global__ __launch_bounds__(256) void k_colmaxsum(
    const float* __restrict__ logits, float* __restrict__ mxsum)
{
    const int e = blockIdx.x, tid = threadIdx.x;
    const int wid = tid >> 6, lane = tid & 63;
    __shared__ float sm[4];
    __shared__ float Mb;

    float m = -INFINITY;
    for (int n = tid; n < NTOK; n += 256) m = fmaxf(m, logits[(size_t)n * NEXP + e]);
    m = waveMax(m);
    if (lane == 0) sm[wid] = m;
    __syncthreads();
    if (tid == 0) Mb = fmaxf(fmaxf(sm[0], sm[1]), fmaxf(sm[2], sm[3]));
    __syncthreads();
    const float M = Mb;

    float s = 0.f;
    for (int n = tid; n < NTOK; n += 256) s += expf(logits[(size_t)n * NEXP + e] - M);
    s = waveSum(s);
    if (lane == 0) sm[wid] = s;
    __syncthreads();
    if (tid == 0) {
        mxsum[e * 2]     = M;
        mxsum[e * 2 + 1] = sm[0] + sm[1] + sm[2] + sm[3];
    }
}

// ---------------- 3. exact top-CAP selection per expert (radix histogram) ----------------
__device__ __forceinline__ unsigned fkey(float f) {
    unsigned u = __float_as_uint(f);
    return (u & 0x80000000u) ? ~u : (u | 0x80000000u);   // monotone increasing
}

__global__ __launch_bounds__(1024) void k_topk(
    const float* __restrict__ logits, const float* __restrict__ mxsum,
    int* __restrict__ top_idx, float* __restrict__ top_prob, float* __restrict__ counts)
{
    const int e = blockIdx.x, tid = threadIdx.x;
    __shared__ unsigned hist[256];
    __shared__ unsigned s_prefix, s_rem, s_cnt_gt, s_cnt_eq;
    if (tid == 0) { s_prefix = 0u; s_rem = CAP; s_cnt_gt = 0u; s_cnt_eq = 0u; }

    for (int pass = 0; pass < 4; ++pass) {
        const int shift = 24 - 8 * pass;
        if (tid < 256) hist[tid] = 0u;
        __syncthreads();
        const unsigned pref = s_prefix;
        for (int n = tid; n < NTOK; n += 1024) {
            const unsigned k = fkey(logits[(size_t)n * NEXP + e]);
            bool cand = true;
            if (pass > 0) cand = ((k >> (shift + 8)) == (pref >> (shift + 8)));
            if (cand) atomicAdd(&hist[(k >> shift) & 255u], 1u);
        }
        __syncthreads();
        if (tid == 0) {
            unsigned rem = s_rem, cum = 0u;
            int d = 0;
            for (d = 255; d >= 0; --d) {
                unsigned c = hist[d];
                if (cum + c >= rem) break;
                cum += c;
            }
            s_rem = rem - cum;
            s_prefix = pref | ((unsigned)d << shift);
        }
        __syncthreads();
    }
    const unsigned T = s_prefix;
    const unsigned rem = s_rem;          // how many ==T to take
    const unsigned n_gt = CAP - rem;     // count strictly greater than T
    const float M = mxsum[e * 2];
    const float invS = 1.0f / mxsum[e * 2 + 1];

    for (int n = tid; n < NTOK; n += 1024) {
        const float l = logits[(size_t)n * NEXP + e];
        const unsigned k = fkey(l);
        int slot = -1;
        if (k > T) slot = (int)atomicAdd(&s_cnt_gt, 1u);
        else if (k == T) {
            unsigned t = atomicAdd(&s_cnt_eq, 1u);
            if (t < rem) slot = (int)(n_gt + t);
        }
        if (slot >= 0) {
            const float p = expf(l - M) * invS;
            top_idx [e * CAP + slot] = n;
            top_prob[e * CAP + slot] = p;
            atomicAdd(&counts[n], p);
        }
    }
}

// ---------------- 4. gate+up fused GEMM (per expert): h = silu(xe@wgT)*(xe@wuT) ----------------
__global__ __launch_bounds__(256) void k_gateup(
    const float* __restrict__ x, const float* __restrict__ wg,
    const float* __restrict__ wu, const int* __restrict__ top_idx,
    float* __restrict__ hbuf, int e)
{
    __shared__ __align__(16) float As[BK][LDST];
    __shared__ __align__(16) float Gs[BK][LDST];
    __shared__ __align__(16) float Us[BK][LDST];

    const int tid = threadIdx.x;
    const int c0 = blockIdx.y * BM;      // token-slot tile
    const int i0 = blockIdx.x * BN;      // inter-dim tile
    const int lm = tid >> 2;             // staged row 0..63
    const int lk = (tid & 3) * 4;        // staged k offset 0,4,8,12

    const int tok = top_idx[e * CAP + c0 + lm];
    const float* xrow = x  + (size_t)tok * HID + lk;
    const float* grow = wg + (size_t)e * INTER * HID + (size_t)(i0 + lm) * HID + lk;
    const float* urow = wu + (size_t)e * INTER * HID + (size_t)(i0 + lm) * HID + lk;

    const int ty = tid >> 4, tx = tid & 15;
    float accg[4][4] = {{0}}, accu[4][4] = {{0}};

    for (int k0 = 0; k0 < HID; k0 += BK) {
        const float4 a = *(const float4*)(xrow + k0);
        const float4 g = *(const float4*)(grow + k0);
        const float4 u = *(const float4*)(urow + k0);
        __syncthreads();
        As[lk+0][lm] = a.x; As[lk+1][lm] = a.y; As[lk+2][lm] = a.z; As[lk+3][lm] = a.w;
        Gs[lk+0][lm] = g.x; Gs[lk+1][lm] = g.y; Gs[lk+2][lm] = g.z; Gs[lk+3][lm] = g.w;
        Us[lk+0][lm] = u.x; Us[lk+1][lm] = u.y; Us[lk+2][lm] = u.z; Us[lk+3][lm] = u.w;
        __syncthreads();
#pragma unroll
        for (int kk = 0; kk < BK; ++kk) {
            const float4 av = *(const float4*)&As[kk][ty << 2];
            const float4 gv = *(const float4*)&Gs[kk][tx << 2];
            const float4 uv = *(const float4*)&Us[kk][tx << 2];
            const float ar[4] = {av.x, av.y, av.z, av.w};
            const float gr[4] = {gv.x, gv.y, gv.z, gv.w};
            const float ur[4] = {uv.x, uv.y, uv.z, uv.w};
#pragma unroll
            for (int r = 0; r < 4; ++r)
#pragma unroll
                for (int q = 0; q < 4; ++q) {
                    accg[r][q] = fmaf(ar[r], gr[q], accg[r][q]);
                    accu[r][q] = fmaf(ar[r], ur[q], accu[r][q]);
                }
        }
    }

#pragma unroll
    for (int r = 0; r < 4; ++r) {
        const int c = c0 + (ty << 2) + r;
        float4 o;
        float gg, uu;
        gg = accg[r][0]; uu = accu[r][0]; o.x = (gg / (1.0f + expf(-gg))) * uu;
        gg = accg[r][1]; uu = accu[r][1]; o.y = (gg / (1.0f + expf(-gg))) * uu;
        gg = accg[r][2]; uu = accu[r][2]; o.z = (gg / (1.0f + expf(-gg))) * uu;
        gg = accg[r][3]; uu = accu[r][3]; o.w = (gg / (1.0f + expf(-gg))) * uu;
        *(float4*)(hbuf + (size_t)c * INTER + i0 + (tx << 2)) = o;
    }
}

// ---------------- 5. down GEMM + weighted scatter (per expert) ----------------
__global__ __launch_bounds__(256) void k_down(
    const float* __restrict__ hbuf, const float* __restrict__ wd,
    const int* __restrict__ top_idx, const float* __restrict__ top_prob,
    float* __restrict__ out, int e)
{
    __shared__ __align__(16) float As[BK][LDST];
    __shared__ __align__(16) float Bs[BK][LDST];

    const int tid = threadIdx.x;
    const int c0 = blockIdx.y * BM;
    const int h0 = blockIdx.x * BN;
    const int lm = tid >> 2;
    const int lk = (tid & 3) * 4;

    const float* arow = hbuf + (size_t)(c0 + lm) * INTER + lk;
    const float* brow = wd + (size_t)e * HID * INTER + (size_t)(h0 + lm) * INTER + lk;

    const int ty = tid >> 4, tx = tid & 15;
    float acc[4][4] = {{0}};

    for (int k0 = 0; k0 < INTER; k0 += BK) {
        const float4 a = *(const float4*)(arow + k0);
        const float4 b = *(const float4*)(brow + k0);
        __syncthreads();
        As[lk+0][lm] = a.x; As[lk+1][lm] = a.y; As[lk+2][lm] = a.z; As[lk+3][lm] = a.w;
        Bs[lk+0][lm] = b.x; Bs[lk+1][lm] = b.y; Bs[lk+2][lm] = b.z; Bs[lk+3][lm] = b.w;
        __syncthreads();
#pragma unroll
        for (int kk = 0; kk < BK; ++kk) {
            const float4 av = *(const float4*)&As[kk][ty << 2];
            const float4 bv = *(const float4*)&Bs[kk][tx << 2];
            const float ar[4] = {av.x, av.y, av.z, av.w};
            const float br[4] = {bv.x, bv.y, bv.z, bv.w};
#pragma unroll
            for (int r = 0; r < 4; ++r)
#pragma unroll
                for (int q = 0; q < 4; ++q)
                    acc[r][q] = fmaf(ar[r], br[q], acc[r][q]);
        }
    }

#pragma unroll
    for (int r = 0; r < 4; ++r) {
        const int c = c0 + (ty << 2) + r;
        const int tok = top_idx[e * CAP + c];
        const float p = top_prob[e * CAP + c];
        float* op = out + (size_t)tok * HID + h0 + (tx << 2);
        float4 cur = *(float4*)op;            // experts serialized on stream: no race
        cur.x += p * acc[r][0];
        cur.y += p * acc[r][1];
        cur.z += p * acc[r][2];
        cur.w += p * acc[r][3];
        *(float4*)op = cur;
    }
}

// ---------------- 6. finalize: out /= clip(counts, EPS); write aux ----------------
__global__ __launch_bounds__(256) void k_final(
    float* __restrict__ out, const float* __restrict__ counts,
    const float* __restrict__ aux)
{
    const int i = blockIdx.x * 256 + threadIdx.x;     // over NTOK*HID/4 float4s
    const int n = i >> 8;                             // H/4 = 256 float4s per row
    const float c = fmaxf(counts[n], EPSF);
    float4* o4 = (float4*)out;
    float4 v = o4[i];
    v.x /= c; v.y /= c; v.z /= c; v.w /= c;
    o4[i] = v;
    if (i == 0) out[(size_t)NTOK * HID] = aux[0] * 0.001f / (float)NTOK;
}

// ---------------- host ----------------
extern "C" void kernel_launch(void* const* d_in, const int* in_sizes, int n_in,
                              void* d_out, int out_size, void* d_ws, size_t ws_size,
                              hipStream_t stream)
{
    const float* x     = (const float*)d_in[0];
    const float* gamma = (const float*)d_in[1];
    const float* beta  = (const float*)d_in[2];
    const float* gw    = (const float*)d_in[3];
    const float* wg    = (const float*)d_in[4];
    const float* wu    = (const float*)d_in[5];
    const float* wd    = (const float*)d_in[6];
    float* out = (float*)d_out;

    char* w = (char*)d_ws;
    size_t off = 0;
    float* counts = (float*)(w + off); off += (size_t)NTOK * 4;            // 64 KB
    float* aux    = (float*)(w + off); off += 256;
    float* logits = (float*)(w + off); off += (size_t)NTOK * NEXP * 4;     // 512 KB
    float* mxsum  = (float*)(w + off); off += 256;
    int*   tidx   = (int*)  (w + off); off += (size_t)NEXP * CAP * 4;      // 64 KB
    float* tprob  = (float*)(w + off); off += (size_t)NEXP * CAP * 4;      // 64 KB
    float* hbuf   = (float*)(w + off); off += (size_t)CAP * INTER * 4;     // 23 MB

    // zero-init accumulators (harness poisons ws/d_out with 0xAA each call)
    hipMemsetAsync(d_out, 0, (size_t)NTOK * HID * 4, stream);
    hipMemsetAsync(counts, 0, (size_t)NTOK * 4 + 256, stream);

    k_ln_router<<<NTOK, 256, 0, stream>>>(x, gamma, beta, gw, logits, aux);
    k_colmaxsum<<<NEXP, 256, 0, stream>>>(logits, mxsum);
    k_topk<<<NEXP, 1024, 0, stream>>>(logits, mxsum, tidx, tprob, counts);

    for (int e = 0; e < NEXP; ++e) {
        k_gateup<<<dim3(INTER / BN, CAP / BM), 256, 0, stream>>>(x, wg, wu, tidx, hbuf, e);
        k_down  <<<dim3(HID   / BN, CAP / BM), 256, 0, stream>>>(hbuf, wd, tidx, tprob, out, e);
    }

    k_final<<<(NTOK * HID / 4) / 256, 256, 0, stream>>>(out, counts, aux);
}

// Round 2
// 2205.785 us; speedup vs baseline: 2.0871x; 2.0871x over previous
//
#include <hip/hip_runtime.h>
#include <hip/hip_bf16.h>
#include <math.h>

#define HID   1024
#define NEXP  8
#define INTER 2816
#define NTOK  16384
#define CAP   2048
#define EPSF  1e-5f

typedef __attribute__((ext_vector_type(8))) short short8v;   // 8 x bf16 bits
typedef __attribute__((ext_vector_type(4))) float floatx4;

typedef const __attribute__((address_space(1))) void* gas_t;
typedef __attribute__((address_space(3))) void* sas_t;

__device__ __forceinline__ void gload16(const void* g, void* l) {
    __builtin_amdgcn_global_load_lds((gas_t)g, (sas_t)l, 16, 0, 0);
}

// ---------------- wave helpers ----------------
__device__ __forceinline__ float waveSum(float v) {
#pragma unroll
    for (int o = 32; o > 0; o >>= 1) v += __shfl_down(v, o);
    return v;
}
__device__ __forceinline__ float waveMax(float v) {
#pragma unroll
    for (int o = 32; o > 0; o >>= 1) v = fmaxf(v, __shfl_down(v, o));
    return v;
}

// ---------------- fp32 -> bf16 hi/lo split ----------------
__global__ __launch_bounds__(256) void k_split(
    const float* __restrict__ src, unsigned short* __restrict__ hi,
    unsigned short* __restrict__ lo, int n4)
{
    int i = blockIdx.x * 256 + threadIdx.x;
    const int stride = gridDim.x * 256;
    for (; i < n4; i += stride) {
        const float4 v = ((const float4*)src)[i];
        float f[4] = {v.x, v.y, v.z, v.w};
        unsigned short hh[4], ll[4];
#pragma unroll
        for (int j = 0; j < 4; ++j) {
            __hip_bfloat16 hb = __float2bfloat16(f[j]);
            float hf = __bfloat162float(hb);
            __hip_bfloat16 lb = __float2bfloat16(f[j] - hf);
            hh[j] = *(unsigned short*)&hb;
            ll[j] = *(unsigned short*)&lb;
        }
        ((ushort4*)hi)[i] = make_ushort4(hh[0], hh[1], hh[2], hh[3]);
        ((ushort4*)lo)[i] = make_ushort4(ll[0], ll[1], ll[2], ll[3]);
    }
}

// ---------------- 1. LayerNorm + router logits + aux(lse^2) ----------------
__global__ __launch_bounds__(256) void k_ln_router(
    const float* __restrict__ x, const float* __restrict__ gamma,
    const float* __restrict__ beta, const float* __restrict__ gw,
    float* __restrict__ logits, float* __restrict__ aux)
{
    const int n   = blockIdx.x;
    const int tid = threadIdx.x;
    const int wid = tid >> 6, lane = tid & 63;

    const float4 xv = *(const float4*)(x + (size_t)n * HID + tid * 4);
    float s  = xv.x + xv.y + xv.z + xv.w;
    float ss = xv.x*xv.x + xv.y*xv.y + xv.z*xv.z + xv.w*xv.w;
    s  = waveSum(s);
    ss = waveSum(ss);

    __shared__ float rs_[4], rss_[4];
    __shared__ float mu_s, rstd_s;
    if (lane == 0) { rs_[wid] = s; rss_[wid] = ss; }
    __syncthreads();
    if (tid == 0) {
        float S  = rs_[0] + rs_[1] + rs_[2] + rs_[3];
        float SS = rss_[0] + rss_[1] + rss_[2] + rss_[3];
        float mu  = S / (float)HID;
        float var = SS / (float)HID - mu * mu;
        mu_s = mu; rstd_s = rsqrtf(var + EPSF);
    }
    __syncthreads();
    const float mu = mu_s, rstd = rstd_s;

    const float4 g = *(const float4*)(gamma + tid * 4);
    const float4 b = *(const float4*)(beta  + tid * 4);
    float xn[4];
    xn[0] = (xv.x - mu) * rstd * g.x + b.x;
    xn[1] = (xv.y - mu) * rstd * g.y + b.y;
    xn[2] = (xv.z - mu) * rstd * g.z + b.z;
    xn[3] = (xv.w - mu) * rstd * g.w + b.w;

    float pl[NEXP];
#pragma unroll
    for (int e = 0; e < NEXP; ++e) {
        const float4 w = *(const float4*)(gw + (size_t)e * HID + tid * 4);
        pl[e] = xn[0]*w.x + xn[1]*w.y + xn[2]*w.z + xn[3]*w.w;
    }

    __shared__ float red[4][NEXP];
#pragma unroll
    for (int e = 0; e < NEXP; ++e) {
        float v = waveSum(pl[e]);
        if (lane == 0) red[wid][e] = v;
    }
    __syncthreads();
    __shared__ float lrow[NEXP];
    if (tid < NEXP) {
        float v = red[0][tid] + red[1][tid] + red[2][tid] + red[3][tid];
        logits[(size_t)n * NEXP + tid] = v;
        lrow[tid] = v;
    }
    __syncthreads();
    if (tid == 0) {
        float m = lrow[0];
#pragma unroll
        for (int e = 1; e < NEXP; ++e) m = fmaxf(m, lrow[e]);
        float se = 0.f;
#pragma unroll
        for (int e = 0; e < NEXP; ++e) se += expf(lrow[e] - m);
        float lse = m + logf(se);
        atomicAdd(aux, lse * lse);
    }
}

// ---------------- 2. per-expert column max & softmax denom ----------------
__global__ __launch_bounds__(256) void k_colmaxsum(
    const float* __restrict__ logits, float* __restrict__ mxsum)
{
    const int e = blockIdx.x, tid = threadIdx.x;
    const int wid = tid >> 6, lane = tid & 63;
    __shared__ float sm[4];
    __shared__ float Mb;

    float m = -INFINITY;
    for (int n = tid; n < NTOK; n += 256) m = fmaxf(m, logits[(size_t)n * NEXP + e]);
    m = waveMax(m);
    if (lane == 0) sm[wid] = m;
    __syncthreads();
    if (tid == 0) Mb = fmaxf(fmaxf(sm[0], sm[1]), fmaxf(sm[2], sm[3]));
    __syncthreads();
    const float M = Mb;

    float s = 0.f;
    for (int n = tid; n < NTOK; n += 256) s += expf(logits[(size_t)n * NEXP + e] - M);
    s = waveSum(s);
    if (lane == 0) sm[wid] = s;
    __syncthreads();
    if (tid == 0) {
        mxsum[e * 2]     = M;
        mxsum[e * 2 + 1] = sm[0] + sm[1] + sm[2] + sm[3];
    }
}

// ---------------- 3. exact top-CAP selection per expert ----------------
__device__ __forceinline__ unsigned fkey(float f) {
    unsigned u = __float_as_uint(f);
    return (u & 0x80000000u) ? ~u : (u | 0x80000000u);
}

__global__ __launch_bounds__(1024) void k_topk(
    const float* __restrict__ logits, const float* __restrict__ mxsum,
    int* __restrict__ top_idx, float* __restrict__ top_prob, float* __restrict__ counts)
{
    const int e = blockIdx.x, tid = threadIdx.x;
    __shared__ unsigned hist[256];
    __shared__ unsigned s_prefix, s_rem, s_cnt_gt, s_cnt_eq;
    if (tid == 0) { s_prefix = 0u; s_rem = CAP; s_cnt_gt = 0u; s_cnt_eq = 0u; }

    for (int pass = 0; pass < 4; ++pass) {
        const int shift = 24 - 8 * pass;
        if (tid < 256) hist[tid] = 0u;
        __syncthreads();
        const unsigned pref = s_prefix;
        for (int n = tid; n < NTOK; n += 1024) {
            const unsigned k = fkey(logits[(size_t)n * NEXP + e]);
            bool cand = true;
            if (pass > 0) cand = ((k >> (shift + 8)) == (pref >> (shift + 8)));
            if (cand) atomicAdd(&hist[(k >> shift) & 255u], 1u);
        }
        __syncthreads();
        if (tid == 0) {
            unsigned rem = s_rem, cum = 0u;
            int d = 0;
            for (d = 255; d >= 0; --d) {
                unsigned c = hist[d];
                if (cum + c >= rem) break;
                cum += c;
            }
            s_rem = rem - cum;
            s_prefix = pref | ((unsigned)d << shift);
        }
        __syncthreads();
    }
    const unsigned T = s_prefix;
    const unsigned rem = s_rem;
    const unsigned n_gt = CAP - rem;
    const float M = mxsum[e * 2];
    const float invS = 1.0f / mxsum[e * 2 + 1];

    for (int n = tid; n < NTOK; n += 1024) {
        const float l = logits[(size_t)n * NEXP + e];
        const unsigned k = fkey(l);
        int slot = -1;
        if (k > T) slot = (int)atomicAdd(&s_cnt_gt, 1u);
        else if (k == T) {
            unsigned t = atomicAdd(&s_cnt_eq, 1u);
            if (t < rem) slot = (int)(n_gt + t);
        }
        if (slot >= 0) {
            const float p = expf(l - M) * invS;
            top_idx [e * CAP + slot] = n;
            top_prob[e * CAP + slot] = p;
            atomicAdd(&counts[n], p);
        }
    }
}

// ---------------- 4. gate+up MFMA GEMM: 256c x 128i tile, BK=64, split bf16 ----------------
// LDS: AHI 32K | ALO 32K | GHI 16K | GLO 16K | UHI 16K | ULO 16K = 128K (dynamic)
__global__ __launch_bounds__(512, 2) void k_gateup_mfma(
    const unsigned short* __restrict__ xhi, const unsigned short* __restrict__ xlo,
    const unsigned short* __restrict__ wghi, const unsigned short* __restrict__ wglo,
    const unsigned short* __restrict__ wuhi, const unsigned short* __restrict__ wulo,
    const int* __restrict__ tidx, __hip_bfloat16* __restrict__ hbuf, int e_base)
{
    extern __shared__ char smem[];
    char* AHI = smem;
    char* ALO = smem + 32 * 1024;
    char* GHI = smem + 64 * 1024;
    char* GLO = smem + 80 * 1024;
    char* UHI = smem + 96 * 1024;
    char* ULO = smem + 112 * 1024;

    const int tid = threadIdx.x;
    const int l = tid & 63, w = tid >> 6;
    const int z = blockIdx.z;
    const int e = e_base + z;
    const int i0 = blockIdx.x * 128;
    const int c0 = blockIdx.y * 256;

    // ---- staging addresses (XOR-swizzled source, linear LDS dest: rule #21) ----
    const int swzg = (((l & 7) ^ (l >> 3)) << 4);
    size_t aOff[4];
#pragma unroll
    for (int j = 0; j < 4; ++j) {
        const int r = (w * 4 + j) * 8 + (l >> 3);
        const int tok = tidx[e * CAP + c0 + r];
        aOff[j] = (size_t)tok * 2048 + swzg;               // hi/lo planes: 1024 bf16/row
    }
    size_t wOff[2];
#pragma unroll
    for (int j = 0; j < 2; ++j) {
        const int r = (w * 2 + j) * 8 + (l >> 3);
        wOff[j] = ((size_t)z * INTER + i0 + r) * 2048 + swzg;
    }

    const int wr = w >> 1, wc = w & 1;
    const int rowA = wr * 64 + (l & 15);
    const int rowB = wc * 64 + (l & 15);
    const int xorr = (l & 7) << 4;
    const int kq = (l >> 4) << 4;

    floatx4 accg[4][4], accu[4][4];
#pragma unroll
    for (int m = 0; m < 4; ++m)
#pragma unroll
        for (int n = 0; n < 4; ++n) {
            accg[m][n] = (floatx4){0.f, 0.f, 0.f, 0.f};
            accu[m][n] = (floatx4){0.f, 0.f, 0.f, 0.f};
        }

    for (int k = 0; k < HID / 64; ++k) {
        __syncthreads();                                   // prev-iter LDS reads done
        const size_t kb = (size_t)k * 128;
#pragma unroll
        for (int j = 0; j < 4; ++j) {
            gload16((const char*)xhi + aOff[j] + kb, AHI + (w * 4 + j) * 1024);
            gload16((const char*)xlo + aOff[j] + kb, ALO + (w * 4 + j) * 1024);
        }
#pragma unroll
        for (int j = 0; j < 2; ++j) {
            gload16((const char*)wghi + wOff[j] + kb, GHI + (w * 2 + j) * 1024);
            gload16((const char*)wglo + wOff[j] + kb, GLO + (w * 2 + j) * 1024);
            gload16((const char*)wuhi + wOff[j] + kb, UHI + (w * 2 + j) * 1024);
            gload16((const char*)wulo + wOff[j] + kb, ULO + (w * 2 + j) * 1024);
        }
        __syncthreads();                                   // vmcnt(0) drained by compiler

#pragma unroll
        for (int s = 0; s < 2; ++s) {
            const int off = (s * 64 + kq) ^ xorr;
            short8v ah[4], al[4];
#pragma unroll
            for (int m = 0; m < 4; ++m) {
                ah[m] = *(const short8v*)(AHI + (rowA + m * 16) * 128 + off);
                al[m] = *(const short8v*)(ALO + (rowA + m * 16) * 128 + off);
            }
            short8v bh[4], bl[4];
#pragma unroll
            for (int n = 0; n < 4; ++n) {
                bh[n] = *(const short8v*)(GHI + (rowB + n * 16) * 128 + off);
                bl[n] = *(const short8v*)(GLO + (rowB + n * 16) * 128 + off);
            }
#pragma unroll
            for (int m = 0; m < 4; ++m)
#pragma unroll
                for (int n = 0; n < 4; ++n) {
                    accg[m][n] = __builtin_amdgcn_mfma_f32_16x16x32_bf16(ah[m], bh[n], accg[m][n], 0, 0, 0);
                    accg[m][n] = __builtin_amdgcn_mfma_f32_16x16x32_bf16(ah[m], bl[n], accg[m][n], 0, 0, 0);
                    accg[m][n] = __builtin_amdgcn_mfma_f32_16x16x32_bf16(al[m], bh[n], accg[m][n], 0, 0, 0);
                }
#pragma unroll
            for (int n = 0; n < 4; ++n) {
                bh[n] = *(const short8v*)(UHI + (rowB + n * 16) * 128 + off);
                bl[n] = *(const short8v*)(ULO + (rowB + n * 16) * 128 + off);
            }
#pragma unroll
            for (int m = 0; m < 4; ++m)
#pragma unroll
                for (int n = 0; n < 4; ++n) {
                    accu[m][n] = __builtin_amdgcn_mfma_f32_16x16x32_bf16(ah[m], bh[n], accu[m][n], 0, 0, 0);
                    accu[m][n] = __builtin_amdgcn_mfma_f32_16x16x32_bf16(ah[m], bl[n], accu[m][n], 0, 0, 0);
                    accu[m][n] = __builtin_amdgcn_mfma_f32_16x16x32_bf16(al[m], bh[n], accu[m][n], 0, 0, 0);
                }
        }
    }

    // epilogue: h = silu(g)*u -> bf16  (C/D: col=lane&15, row=(lane>>4)*4+reg)
#pragma unroll
    for (int m = 0; m < 4; ++m)
#pragma unroll
        for (int n = 0; n < 4; ++n)
#pragma unroll
            for (int r = 0; r < 4; ++r) {
                const int c = c0 + wr * 64 + m * 16 + (l >> 4) * 4 + r;
                const int i = i0 + wc * 64 + n * 16 + (l & 15);
                const float g = accg[m][n][r], u = accu[m][n][r];
                const float h = (g / (1.f + expf(-g))) * u;
                hbuf[((size_t)z * CAP + c) * INTER + i] = __float2bfloat16(h);
            }
}

// ---------------- 5. down MFMA GEMM + weighted atomic scatter: 256c x 128h, BK=64 ----------------
// LDS: AT 32K | BHI 16K | BLO 16K | sTok 1K | sP 1K = 66K (dynamic)
__global__ __launch_bounds__(512, 2) void k_down_mfma(
    const __hip_bfloat16* __restrict__ hbuf,
    const unsigned short* __restrict__ wdhi, const unsigned short* __restrict__ wdlo,
    const int* __restrict__ tidx, const float* __restrict__ tprob,
    float* __restrict__ out, int e_base)
{
    extern __shared__ char smem[];
    char* AT = smem;
    char* BH = smem + 32 * 1024;
    char* BL = smem + 48 * 1024;
    int*   sTok = (int*)(smem + 64 * 1024);
    float* sP   = (float*)(smem + 65 * 1024);

    const int tid = threadIdx.x;
    const int l = tid & 63, w = tid >> 6;
    const int z = blockIdx.z, e = e_base + z;
    const int h0 = blockIdx.x * 128;
    const int c0 = blockIdx.y * 256;

    if (tid < 256) {
        sTok[tid] = tidx[e * CAP + c0 + tid];
        sP[tid]   = tprob[e * CAP + c0 + tid];
    }

    const int swzg = (((l & 7) ^ (l >> 3)) << 4);
    size_t aOff[4];
#pragma unroll
    for (int j = 0; j < 4; ++j) {
        const int r = (w * 4 + j) * 8 + (l >> 3);
        aOff[j] = ((size_t)z * CAP + c0 + r) * (INTER * 2) + swzg;
    }
    size_t bOff[2];
#pragma unroll
    for (int j = 0; j < 2; ++j) {
        const int r = (w * 2 + j) * 8 + (l >> 3);
        bOff[j] = ((size_t)z * HID + h0 + r) * (INTER * 2) + swzg;
    }

    const int wr = w >> 1, wc = w & 1;
    const int rowA = wr * 64 + (l & 15);
    const int rowB = wc * 64 + (l & 15);
    const int xorr = (l & 7) << 4;
    const int kq = (l >> 4) << 4;

    floatx4 acc[4][4];
#pragma unroll
    for (int m = 0; m < 4; ++m)
#pragma unroll
        for (int n = 0; n < 4; ++n) acc[m][n] = (floatx4){0.f, 0.f, 0.f, 0.f};

    for (int k = 0; k < INTER / 64; ++k) {
        __syncthreads();
        const size_t kb = (size_t)k * 128;
#pragma unroll
        for (int j = 0; j < 4; ++j)
            gload16((const char*)hbuf + aOff[j] + kb, AT + (w * 4 + j) * 1024);
#pragma unroll
        for (int j = 0; j < 2; ++j) {
            gload16((const char*)wdhi + bOff[j] + kb, BH + (w * 2 + j) * 1024);
            gload16((const char*)wdlo + bOff[j] + kb, BL + (w * 2 + j) * 1024);
        }
        __syncthreads();

#pragma unroll
        for (int s = 0; s < 2; ++s) {
            const int off = (s * 64 + kq) ^ xorr;
            short8v a[4], bh[4], bl[4];
#pragma unroll
            for (int m = 0; m < 4; ++m)
                a[m] = *(const short8v*)(AT + (rowA + m * 16) * 128 + off);
#pragma unroll
            for (int n = 0; n < 4; ++n) {
                bh[n] = *(const short8v*)(BH + (rowB + n * 16) * 128 + off);
                bl[n] = *(const short8v*)(BL + (rowB + n * 16) * 128 + off);
            }
#pragma unroll
            for (int m = 0; m < 4; ++m)
#pragma unroll
                for (int n = 0; n < 4; ++n) {
                    acc[m][n] = __builtin_amdgcn_mfma_f32_16x16x32_bf16(a[m], bh[n], acc[m][n], 0, 0, 0);
                    acc[m][n] = __builtin_amdgcn_mfma_f32_16x16x32_bf16(a[m], bl[n], acc[m][n], 0, 0, 0);
                }
        }
    }

#pragma unroll
    for (int m = 0; m < 4; ++m)
#pragma unroll
        for (int n = 0; n < 4; ++n)
#pragma unroll
            for (int r = 0; r < 4; ++r) {
                const int cl = wr * 64 + m * 16 + (l >> 4) * 4 + r;
                const int col = h0 + wc * 64 + n * 16 + (l & 15);
                const float v = sP[cl] * acc[m][n][r];
                atomicAdd(&out[(size_t)sTok[cl] * HID + col], v);
            }
}

// ---------------- 6. finalize ----------------
__global__ __launch_bounds__(256) void k_final(
    float* __restrict__ out, const float* __restrict__ counts,
    const float* __restrict__ aux)
{
    const int i = blockIdx.x * 256 + threadIdx.x;
    const int n = i >> 8;
    const float c = fmaxf(counts[n], EPSF);
    float4* o4 = (float4*)out;
    float4 v = o4[i];
    v.x /= c; v.y /= c; v.z /= c; v.w /= c;
    o4[i] = v;
    if (i == 0) out[(size_t)NTOK * HID] = aux[0] * 0.001f / (float)NTOK;
}

// ---------------- host ----------------
extern "C" void kernel_launch(void* const* d_in, const int* in_sizes, int n_in,
                              void* d_out, int out_size, void* d_ws, size_t ws_size,
                              hipStream_t stream)
{
    const float* x     = (const float*)d_in[0];
    const float* gamma = (const float*)d_in[1];
    const float* beta  = (const float*)d_in[2];
    const float* gw    = (const float*)d_in[3];
    const float* wg    = (const float*)d_in[4];
    const float* wu    = (const float*)d_in[5];
    const float* wd    = (const float*)d_in[6];
    float* out = (float*)d_out;

    static bool attr_set = false;
    hipFuncSetAttribute(reinterpret_cast<const void*>(k_gateup_mfma),
                        hipFuncAttributeMaxDynamicSharedMemorySize, 128 * 1024);
    hipFuncSetAttribute(reinterpret_cast<const void*>(k_down_mfma),
                        hipFuncAttributeMaxDynamicSharedMemorySize, 66 * 1024);
    (void)attr_set;

    const size_t NX  = (size_t)NTOK * HID;        // 16.7M
    const size_t NW  = (size_t)NEXP * INTER * HID;// 23.07M per weight tensor

    char* wsb = (char*)d_ws;
    size_t off = 0;
    auto alloc = [&](size_t bytes) -> char* {
        char* r = wsb + off;
        off = (off + bytes + 255) & ~(size_t)255;
        return r;
    };
    float* counts = (float*)alloc((size_t)NTOK * 4);
    float* aux    = (float*)alloc(256);
    float* logits = (float*)alloc((size_t)NTOK * NEXP * 4);
    float* mxsum  = (float*)alloc(256);
    int*   tidx   = (int*)  alloc((size_t)NEXP * CAP * 4);
    float* tprob  = (float*)alloc((size_t)NEXP * CAP * 4);
    unsigned short* xhi = (unsigned short*)alloc(NX * 2);
    unsigned short* xlo = (unsigned short*)alloc(NX * 2);

    // fused-path requirement: 6 full weight planes + full hbuf
    const size_t fused_need = off + 6 * (NW * 2 + 256) +
                              (size_t)NEXP * CAP * INTER * 2 + 256;
    const bool fused = (ws_size >= fused_need);

    hipMemsetAsync(d_out, 0, NX * 4 + 4, stream);
    hipMemsetAsync(counts, 0, (size_t)NTOK * 4 + 256, stream);

    k_split<<<2048, 256, 0, stream>>>(x, xhi, xlo, (int)(NX / 4));
    k_ln_router<<<NTOK, 256, 0, stream>>>(x, gamma, beta, gw, logits, aux);
    k_colmaxsum<<<NEXP, 256, 0, stream>>>(logits, mxsum);
    k_topk<<<NEXP, 1024, 0, stream>>>(logits, mxsum, tidx, tprob, counts);

    if (fused) {
        unsigned short* wghi = (unsigned short*)alloc(NW * 2);
        unsigned short* wglo = (unsigned short*)alloc(NW * 2);
        unsigned short* wuhi = (unsigned short*)alloc(NW * 2);
        unsigned short* wulo = (unsigned short*)alloc(NW * 2);
        unsigned short* wdhi = (unsigned short*)alloc(NW * 2);
        unsigned short* wdlo = (unsigned short*)alloc(NW * 2);
        __hip_bfloat16* hbuf = (__hip_bfloat16*)alloc((size_t)NEXP * CAP * INTER * 2);

        k_split<<<2048, 256, 0, stream>>>(wg, wghi, wglo, (int)(NW / 4));
        k_split<<<2048, 256, 0, stream>>>(wu, wuhi, wulo, (int)(NW / 4));
        k_split<<<2048, 256, 0, stream>>>(wd, wdhi, wdlo, (int)(NW / 4));

        k_gateup_mfma<<<dim3(INTER / 128, CAP / 256, NEXP), 512, 128 * 1024, stream>>>(
            xhi, xlo, wghi, wglo, wuhi, wulo, tidx, hbuf, 0);
        k_down_mfma<<<dim3(HID / 128, CAP / 256, NEXP), 512, 66 * 1024, stream>>>(
            hbuf, wdhi, wdlo, tidx, tprob, out, 0);
    } else {
        const size_t NW1 = (size_t)INTER * HID;   // one expert
        unsigned short* wghi = (unsigned short*)alloc(NW1 * 2);
        unsigned short* wglo = (unsigned short*)alloc(NW1 * 2);
        unsigned short* wuhi = (unsigned short*)alloc(NW1 * 2);
        unsigned short* wulo = (unsigned short*)alloc(NW1 * 2);
        unsigned short* wdhi = (unsigned short*)alloc(NW1 * 2);
        unsigned short* wdlo = (unsigned short*)alloc(NW1 * 2);
        __hip_bfloat16* hbuf = (__hip_bfloat16*)alloc((size_t)CAP * INTER * 2);

        for (int e = 0; e < NEXP; ++e) {
            k_split<<<1024, 256, 0, stream>>>(wg + (size_t)e * NW1, wghi, wglo, (int)(NW1 / 4));
            k_split<<<1024, 256, 0, stream>>>(wu + (size_t)e * NW1, wuhi, wulo, (int)(NW1 / 4));
            k_split<<<1024, 256, 0, stream>>>(wd + (size_t)e * NW1, wdhi, wdlo, (int)(NW1 / 4));
            k_gateup_mfma<<<dim3(INTER / 128, CAP / 256, 1), 512, 128 * 1024, stream>>>(
                xhi, xlo, wghi, wglo, wuhi, wulo, tidx, hbuf, e);
            k_down_mfma<<<dim3(HID / 128, CAP / 256, 1), 512, 66 * 1024, stream>>>(
                hbuf, wdhi, wdlo, tidx, tprob, out, e);
        }
    }

    k_final<<<(NTOK * HID / 4) / 256, 256, 0, stream>>>(out, counts, aux);
}

// Round 4
// 1153.460 us; speedup vs baseline: 3.9912x; 1.9123x over previous
//
#include <hip/hip_runtime.h>
#include <hip/hip_bf16.h>
#include <math.h>

#define HID   1024
#define NEXP  8
#define INTER 2816
#define NTOK  16384
#define CAP   2048
#define EPSF  1e-5f

typedef unsigned short ushort_t;
typedef __attribute__((ext_vector_type(8))) short short8v;   // 8 x bf16 bits
typedef __attribute__((ext_vector_type(4))) float floatx4;

typedef const __attribute__((address_space(1))) void* gas_t;
typedef __attribute__((address_space(3))) void* sas_t;

__device__ __forceinline__ void gload16(const void* g, void* l) {
    __builtin_amdgcn_global_load_lds((gas_t)g, (sas_t)l, 16, 0, 0);
}

__device__ __forceinline__ ushort_t f2bf(float f) {
    __hip_bfloat16 h = __float2bfloat16(f);
    return *(ushort_t*)&h;
}

// ============ 1. fused LayerNorm + router + x hi/lo split (wave per token) ============
__global__ __launch_bounds__(256) void k_ln_split_router(
    const float* __restrict__ x, const float* __restrict__ gamma,
    const float* __restrict__ beta, const float* __restrict__ gw,
    ushort_t* __restrict__ xhi, ushort_t* __restrict__ xlo,
    float* __restrict__ logits, float* __restrict__ aux)
{
    const int tid = threadIdx.x;
    const int l = tid & 63, wid = tid >> 6;
    const int gwave = blockIdx.x * 4 + wid;       // 2048 waves
    __shared__ float sred[4];

    // per-lane gamma/beta (cols l*16 .. l*16+15), loop-invariant
    float4 gm[4], bt[4];
#pragma unroll
    for (int j = 0; j < 4; ++j) {
        gm[j] = *(const float4*)(gamma + l * 16 + j * 4);
        bt[j] = *(const float4*)(beta  + l * 16 + j * 4);
    }

    float lse2 = 0.f;
    for (int n = gwave * 8; n < (gwave + 1) * 8; ++n) {
        float4 xv[4];
#pragma unroll
        for (int j = 0; j < 4; ++j)
            xv[j] = *(const float4*)(x + (size_t)n * HID + l * 16 + j * 4);

        float s = 0.f, ss = 0.f;
#pragma unroll
        for (int j = 0; j < 4; ++j) {
            s  += xv[j].x + xv[j].y + xv[j].z + xv[j].w;
            ss += xv[j].x*xv[j].x + xv[j].y*xv[j].y + xv[j].z*xv[j].z + xv[j].w*xv[j].w;
        }
#pragma unroll
        for (int o = 1; o < 64; o <<= 1) {
            s  += __shfl_xor(s, o);
            ss += __shfl_xor(ss, o);
        }
        const float mu = s / (float)HID;
        const float rstd = rsqrtf(ss / (float)HID - mu * mu + EPSF);

        // write hi/lo split of RAW x (xe gathers raw hidden states in the reference)
        float xn[16];
#pragma unroll
        for (int half = 0; half < 2; ++half) {
            unsigned pk_h[4], pk_l[4];
#pragma unroll
            for (int j = 0; j < 2; ++j) {
                const float4 v = xv[half * 2 + j];
                const float f[4] = {v.x, v.y, v.z, v.w};
                unsigned h2[2], l2[2];
#pragma unroll
                for (int q = 0; q < 2; ++q) {
                    float a = f[q * 2], b = f[q * 2 + 1];
                    ushort_t ha = f2bf(a), hb = f2bf(b);
                    float fa, fb;
                    *(unsigned*)&fa = (unsigned)ha << 16;
                    *(unsigned*)&fb = (unsigned)hb << 16;
                    ushort_t la = f2bf(a - fa), lb = f2bf(b - fb);
                    h2[q] = (unsigned)ha | ((unsigned)hb << 16);
                    l2[q] = (unsigned)la | ((unsigned)lb << 16);
                }
                pk_h[j * 2] = h2[0]; pk_h[j * 2 + 1] = h2[1];
                pk_l[j * 2] = l2[0]; pk_l[j * 2 + 1] = l2[1];
            }
            *(uint4*)(xhi + (size_t)n * HID + l * 16 + half * 8) =
                make_uint4(pk_h[0], pk_h[1], pk_h[2], pk_h[3]);
            *(uint4*)(xlo + (size_t)n * HID + l * 16 + half * 8) =
                make_uint4(pk_l[0], pk_l[1], pk_l[2], pk_l[3]);
        }
#pragma unroll
        for (int j = 0; j < 4; ++j) {
            const float4 v = xv[j];
            xn[j*4+0] = (v.x - mu) * rstd * gm[j].x + bt[j].x;
            xn[j*4+1] = (v.y - mu) * rstd * gm[j].y + bt[j].y;
            xn[j*4+2] = (v.z - mu) * rstd * gm[j].z + bt[j].z;
            xn[j*4+3] = (v.w - mu) * rstd * gm[j].w + bt[j].w;
        }

        float pl[NEXP];
#pragma unroll
        for (int e = 0; e < NEXP; ++e) {
            float acc = 0.f;
#pragma unroll
            for (int j = 0; j < 4; ++j) {
                const float4 w = *(const float4*)(gw + (size_t)e * HID + l * 16 + j * 4);
                acc += xn[j*4+0]*w.x + xn[j*4+1]*w.y + xn[j*4+2]*w.z + xn[j*4+3]*w.w;
            }
#pragma unroll
            for (int o = 1; o < 64; o <<= 1) acc += __shfl_xor(acc, o);
            pl[e] = acc;
        }
        if (l == 0) {
#pragma unroll
            for (int e = 0; e < NEXP; ++e) logits[(size_t)n * NEXP + e] = pl[e];
            float m = pl[0];
#pragma unroll
            for (int e = 1; e < NEXP; ++e) m = fmaxf(m, pl[e]);
            float se = 0.f;
#pragma unroll
            for (int e = 0; e < NEXP; ++e) se += expf(pl[e] - m);
            const float lse = m + logf(se);
            lse2 += lse * lse;
        }
    }
    // one atomic per block
    if (l == 0) sred[wid] = lse2;
    __syncthreads();
    if (tid == 0) atomicAdd(aux, sred[0] + sred[1] + sred[2] + sred[3]);
}

// ============ 2. per-expert column max & softmax denom ============
__global__ __launch_bounds__(256) void k_colmaxsum(
    const float* __restrict__ logits, float* __restrict__ mxsum)
{
    const int e = blockIdx.x, tid = threadIdx.x;
    const int wid = tid >> 6, lane = tid & 63;
    __shared__ float sm[4];
    __shared__ float Mb;

    float m = -INFINITY;
    for (int n = tid; n < NTOK; n += 256) m = fmaxf(m, logits[(size_t)n * NEXP + e]);
#pragma unroll
    for (int o = 32; o > 0; o >>= 1) m = fmaxf(m, __shfl_down(m, o));
    if (lane == 0) sm[wid] = m;
    __syncthreads();
    if (tid == 0) Mb = fmaxf(fmaxf(sm[0], sm[1]), fmaxf(sm[2], sm[3]));
    __syncthreads();
    const float M = Mb;

    float s = 0.f;
    for (int n = tid; n < NTOK; n += 256) s += expf(logits[(size_t)n * NEXP + e] - M);
#pragma unroll
    for (int o = 32; o > 0; o >>= 1) s += __shfl_down(s, o);
    if (lane == 0) sm[wid] = s;
    __syncthreads();
    if (tid == 0) {
        mxsum[e * 2]     = M;
        mxsum[e * 2 + 1] = sm[0] + sm[1] + sm[2] + sm[3];
    }
}

// ============ 3. exact top-CAP selection per expert (radix histogram) ============
__device__ __forceinline__ unsigned fkey(float f) {
    unsigned u = __float_as_uint(f);
    return (u & 0x80000000u) ? ~u : (u | 0x80000000u);
}

__global__ __launch_bounds__(1024) void k_topk(
    const float* __restrict__ logits, const float* __restrict__ mxsum,
    int* __restrict__ top_idx, float* __restrict__ top_prob, float* __restrict__ counts)
{
    const int e = blockIdx.x, tid = threadIdx.x;
    __shared__ unsigned hist[256];
    __shared__ unsigned s_prefix, s_rem, s_cnt_gt, s_cnt_eq;
    if (tid == 0) { s_prefix = 0u; s_rem = CAP; s_cnt_gt = 0u; s_cnt_eq = 0u; }

    for (int pass = 0; pass < 4; ++pass) {
        const int shift = 24 - 8 * pass;
        if (tid < 256) hist[tid] = 0u;
        __syncthreads();
        const unsigned pref = s_prefix;
        for (int n = tid; n < NTOK; n += 1024) {
            const unsigned k = fkey(logits[(size_t)n * NEXP + e]);
            bool cand = true;
            if (pass > 0) cand = ((k >> (shift + 8)) == (pref >> (shift + 8)));
            if (cand) atomicAdd(&hist[(k >> shift) & 255u], 1u);
        }
        __syncthreads();
        if (tid == 0) {
            unsigned rem = s_rem, cum = 0u;
            int d = 0;
            for (d = 255; d >= 0; --d) {
                unsigned c = hist[d];
                if (cum + c >= rem) break;
                cum += c;
            }
            s_rem = rem - cum;
            s_prefix = pref | ((unsigned)d << shift);
        }
        __syncthreads();
    }
    const unsigned T = s_prefix;
    const unsigned rem = s_rem;
    const unsigned n_gt = CAP - rem;
    const float M = mxsum[e * 2];
    const float invS = 1.0f / mxsum[e * 2 + 1];

    for (int n = tid; n < NTOK; n += 1024) {
        const float lg = logits[(size_t)n * NEXP + e];
        const unsigned k = fkey(lg);
        int slot = -1;
        if (k > T) slot = (int)atomicAdd(&s_cnt_gt, 1u);
        else if (k == T) {
            unsigned t = atomicAdd(&s_cnt_eq, 1u);
            if (t < rem) slot = (int)(n_gt + t);
        }
        if (slot >= 0) {
            const float p = expf(lg - M) * invS;
            top_idx [e * CAP + slot] = n;
            top_prob[e * CAP + slot] = p;
            atomicAdd(&counts[n], p);
        }
    }
}

// ============ 4. fp32 -> bf16 hi/lo split (weights) ============
__global__ __launch_bounds__(256) void k_split(
    const float* __restrict__ src, ushort_t* __restrict__ hi,
    ushort_t* __restrict__ lo, int n4)
{
    int i = blockIdx.x * 256 + threadIdx.x;
    const int stride = gridDim.x * 256;
    for (; i < n4; i += stride) {
        const float4 v = ((const float4*)src)[i];
        const float f[4] = {v.x, v.y, v.z, v.w};
        ushort_t hh[4], ll[4];
#pragma unroll
        for (int j = 0; j < 4; ++j) {
            ushort_t h = f2bf(f[j]);
            float hf; *(unsigned*)&hf = (unsigned)h << 16;
            hh[j] = h;
            ll[j] = f2bf(f[j] - hf);
        }
        ((ushort4*)hi)[i] = make_ushort4(hh[0], hh[1], hh[2], hh[3]);
        ((ushort4*)lo)[i] = make_ushort4(ll[0], ll[1], ll[2], ll[3]);
    }
}

// ============ 5. gate+up MFMA GEMM: 256c x 128i, BK=32, dbuf, merged hi|lo rows ============
// plane row = 128 B = 8 x 16B slots: slots 0-3 = hi k0..31, 4-7 = lo k0..31,
// physical slot = logical ^ (row&7).  LDS: 2 x (A 32K | G 16K | U 16K) = 128 KB.
__global__ __launch_bounds__(512, 2) void k_gateup2(
    const ushort_t* __restrict__ xhi,                 // xlo = xhi + NTOK*HID
    const ushort_t* __restrict__ wghi,                // wglo = wghi + G*INTER*HID
    const ushort_t* __restrict__ wuhi,
    const int* __restrict__ tidx, ushort_t* __restrict__ hbuf,
    int e_base, int nE)
{
    extern __shared__ char smem[];
    const int tid = threadIdx.x;
    const int l = tid & 63, w = tid >> 6;
    const int z = blockIdx.z, e = e_base + z;
    const int i0 = blockIdx.x * 128;
    const int c0 = blockIdx.y * 256;

    const size_t loX = (size_t)NTOK * HID * 2;        // byte offset hi->lo plane
    const size_t loW = (size_t)nE * INTER * HID * 2;

    // staging source offsets (pre-swizzled global source, linear LDS dest)
    const int jj = (l & 7) ^ (l >> 3);                // logical slot 0..7
    const int cA = jj & 3;                            // k-chunk 0..3
    const size_t selX = (jj < 4) ? 0 : loX;
    const size_t selW = (jj < 4) ? 0 : loW;

    size_t aSrc[4];
#pragma unroll
    for (int q = 0; q < 4; ++q) {
        const int r = (w * 4 + q) * 8 + (l >> 3);
        const int tok = tidx[e * CAP + c0 + r];
        aSrc[q] = selX + (size_t)tok * 2048 + cA * 16;
    }
    size_t gSrc[2], uSrc[2];
#pragma unroll
    for (int q = 0; q < 2; ++q) {
        const int r = (w * 2 + q) * 8 + (l >> 3);
        const size_t rowoff = ((size_t)z * INTER + i0 + r) * 2048 + cA * 16;
        gSrc[q] = selW + rowoff;
        uSrc[q] = selW + rowoff;
    }

    // fragment read offsets
    const int wr = w >> 2, wc = w & 3;                // 2 x 4 waves
    const int rowA = wr * 128 + (l & 15);
    const int rowB = wc * 32 + (l & 15);
    const int physHi = ((l >> 4) ^ (l & 7)) * 16;
    const int physLo = physHi ^ 64;                   // ^4 slots = ^64 bytes

    floatx4 accg[8][2], accu[8][2];
#pragma unroll
    for (int m = 0; m < 8; ++m)
#pragma unroll
        for (int n = 0; n < 2; ++n) {
            accg[m][n] = (floatx4){0.f,0.f,0.f,0.f};
            accu[m][n] = (floatx4){0.f,0.f,0.f,0.f};
        }

    // ---- staging: K-step kk into buffer b ----
    auto STAGE = [&](int b, int kk) {
        char* A = smem + b * 65536;
        char* G = A + 32768;
        char* U = G + 16384;
        const size_t kb = (size_t)kk * 64;            // kk*32 elems * 2B
#pragma unroll
        for (int q = 0; q < 4; ++q)
            gload16((const char*)xhi + aSrc[q] + kb, A + (w * 4 + q) * 1024);
#pragma unroll
        for (int q = 0; q < 2; ++q) {
            gload16((const char*)wghi + gSrc[q] + kb, G + (w * 2 + q) * 1024);
            gload16((const char*)wuhi + uSrc[q] + kb, U + (w * 2 + q) * 1024);
        }
    };

    STAGE(0, 0);
    __syncthreads();

    const int NK = HID / 32;                          // 32
    int cur = 0;
    for (int t = 0; t < NK; ++t) {
        if (t + 1 < NK) STAGE(cur ^ 1, t + 1);

        const char* A = smem + cur * 65536;
        const char* G = A + 32768;
        const char* U = G + 16384;

        short8v ah[8], al[8];
#pragma unroll
        for (int m = 0; m < 8; ++m) {
            const int rb = (rowA + m * 16) * 128;
            ah[m] = *(const short8v*)(A + rb + physHi);
            al[m] = *(const short8v*)(A + rb + physLo);
        }
#pragma unroll
        for (int n = 0; n < 2; ++n) {
            const int rb = (rowB + n * 16) * 128;
            const short8v gh = *(const short8v*)(G + rb + physHi);
            const short8v gl = *(const short8v*)(G + rb + physLo);
            const short8v uh = *(const short8v*)(U + rb + physHi);
            const short8v ul = *(const short8v*)(U + rb + physLo);
#pragma unroll
            for (int m = 0; m < 8; ++m) {
                accg[m][n] = __builtin_amdgcn_mfma_f32_16x16x32_bf16(ah[m], gh, accg[m][n], 0, 0, 0);
                accg[m][n] = __builtin_amdgcn_mfma_f32_16x16x32_bf16(ah[m], gl, accg[m][n], 0, 0, 0);
                accg[m][n] = __builtin_amdgcn_mfma_f32_16x16x32_bf16(al[m], gh, accg[m][n], 0, 0, 0);
                accu[m][n] = __builtin_amdgcn_mfma_f32_16x16x32_bf16(ah[m], uh, accu[m][n], 0, 0, 0);
                accu[m][n] = __builtin_amdgcn_mfma_f32_16x16x32_bf16(ah[m], ul, accu[m][n], 0, 0, 0);
                accu[m][n] = __builtin_amdgcn_mfma_f32_16x16x32_bf16(al[m], uh, accu[m][n], 0, 0, 0);
            }
        }
        __syncthreads();
        cur ^= 1;
    }

    // epilogue: h = silu(g)*u -> bf16   (C/D: col=lane&15, row=(lane>>4)*4+reg)
#pragma unroll
    for (int m = 0; m < 8; ++m)
#pragma unroll
        for (int n = 0; n < 2; ++n)
#pragma unroll
            for (int r = 0; r < 4; ++r) {
                const int c = c0 + wr * 128 + m * 16 + (l >> 4) * 4 + r;
                const int i = i0 + wc * 32 + n * 16 + (l & 15);
                const float g = accg[m][n][r], u = accu[m][n][r];
                const float h = (g / (1.f + expf(-g))) * u;
                hbuf[((size_t)z * CAP + c) * INTER + i] = f2bf(h);
            }
}

// ============ 6. down MFMA GEMM + weighted atomic scatter: 256c x 128h, BK=64, dbuf ============
// LDS: 2 x (A 32K | BH 16K | BL 16K) = 128 KB + sTok/sP 2 KB
__global__ __launch_bounds__(512, 2) void k_down2(
    const ushort_t* __restrict__ hbuf,
    const ushort_t* __restrict__ wdhi,                // wdlo = wdhi + G*HID*INTER
    const int* __restrict__ tidx, const float* __restrict__ tprob,
    float* __restrict__ out, int e_base, int nE)
{
    extern __shared__ char smem[];
    int*   sTok = (int*)(smem + 131072);
    float* sP   = (float*)(smem + 132096);

    const int tid = threadIdx.x;
    const int l = tid & 63, w = tid >> 6;
    const int z = blockIdx.z, e = e_base + z;
    const int h0 = blockIdx.x * 128;
    const int c0 = blockIdx.y * 256;

    if (tid < 256) {
        sTok[tid] = tidx[e * CAP + c0 + tid];
        sP[tid]   = tprob[e * CAP + c0 + tid];
    }

    const size_t loW = (size_t)nE * HID * INTER * 2;
    const int jj = (l & 7) ^ (l >> 3);                // chunk 0..7 (full BK=64)

    size_t aSrc[4];
#pragma unroll
    for (int q = 0; q < 4; ++q) {
        const int r = (w * 4 + q) * 8 + (l >> 3);
        aSrc[q] = ((size_t)(z * CAP + c0 + r) * INTER + jj * 8) * 2;
    }
    size_t bSrc[2];
#pragma unroll
    for (int q = 0; q < 2; ++q) {
        const int r = (w * 2 + q) * 8 + (l >> 3);
        bSrc[q] = ((size_t)(z * HID + h0 + r) * INTER + jj * 8) * 2;
    }

    const int wr = w >> 2, wc = w & 3;
    const int rowA = wr * 128 + (l & 15);
    const int rowB = wc * 32 + (l & 15);
    const int kq16 = (l >> 4) * 16;
    const int xorr = (l & 7) * 16;

    floatx4 acc[8][2];
#pragma unroll
    for (int m = 0; m < 8; ++m)
#pragma unroll
        for (int n = 0; n < 2; ++n) acc[m][n] = (floatx4){0.f,0.f,0.f,0.f};

    auto STAGE = [&](int b, int kk) {
        char* A  = smem + b * 65536;
        char* BH = A + 32768;
        char* BL = BH + 16384;
        const size_t kb = (size_t)kk * 128;           // kk*64 elems * 2B
#pragma unroll
        for (int q = 0; q < 4; ++q)
            gload16((const char*)hbuf + aSrc[q] + kb, A + (w * 4 + q) * 1024);
#pragma unroll
        for (int q = 0; q < 2; ++q) {
            gload16((const char*)wdhi + bSrc[q] + kb,       BH + (w * 2 + q) * 1024);
            gload16((const char*)wdhi + loW + bSrc[q] + kb, BL + (w * 2 + q) * 1024);
        }
    };

    STAGE(0, 0);
    __syncthreads();

    const int NK = INTER / 64;                        // 44
    int cur = 0;
    for (int t = 0; t < NK; ++t) {
        if (t + 1 < NK) STAGE(cur ^ 1, t + 1);

        const char* A  = smem + cur * 65536;
        const char* BH = A + 32768;
        const char* BL = BH + 16384;

#pragma unroll
        for (int s = 0; s < 2; ++s) {
            const int off = (s * 64 + kq16) ^ xorr;
            short8v a[8];
#pragma unroll
            for (int m = 0; m < 8; ++m)
                a[m] = *(const short8v*)(A + (rowA + m * 16) * 128 + off);
#pragma unroll
            for (int n = 0; n < 2; ++n) {
                const int rb = (rowB + n * 16) * 128 + off;
                const short8v bh = *(const short8v*)(BH + rb);
                const short8v bl = *(const short8v*)(BL + rb);
#pragma unroll
                for (int m = 0; m < 8; ++m) {
                    acc[m][n] = __builtin_amdgcn_mfma_f32_16x16x32_bf16(a[m], bh, acc[m][n], 0, 0, 0);
                    acc[m][n] = __builtin_amdgcn_mfma_f32_16x16x32_bf16(a[m], bl, acc[m][n], 0, 0, 0);
                }
            }
        }
        __syncthreads();
        cur ^= 1;
    }

#pragma unroll
    for (int m = 0; m < 8; ++m)
#pragma unroll
        for (int n = 0; n < 2; ++n)
#pragma unroll
            for (int r = 0; r < 4; ++r) {
                const int cl = wr * 128 + m * 16 + (l >> 4) * 4 + r;
                const int col = h0 + wc * 32 + n * 16 + (l & 15);
                const float v = sP[cl] * acc[m][n][r];
                atomicAdd(&out[(size_t)sTok[cl] * HID + col], v);
            }
}

// ============ 7. finalize ============
__global__ __launch_bounds__(256) void k_final(
    float* __restrict__ out, const float* __restrict__ counts,
    const float* __restrict__ aux)
{
    const int i = blockIdx.x * 256 + threadIdx.x;
    const int n = i >> 8;
    const float c = fmaxf(counts[n], EPSF);
    float4* o4 = (float4*)out;
    float4 v = o4[i];
    v.x /= c; v.y /= c; v.z /= c; v.w /= c;
    o4[i] = v;
    if (i == 0) out[(size_t)NTOK * HID] = aux[0] * 0.001f / (float)NTOK;
}

// ============ host ============
extern "C" void kernel_launch(void* const* d_in, const int* in_sizes, int n_in,
                              void* d_out, int out_size, void* d_ws, size_t ws_size,
                              hipStream_t stream)
{
    const float* x     = (const float*)d_in[0];
    const float* gamma = (const float*)d_in[1];
    const float* beta  = (const float*)d_in[2];
    const float* gw    = (const float*)d_in[3];
    const float* wg    = (const float*)d_in[4];
    const float* wu    = (const float*)d_in[5];
    const float* wd    = (const float*)d_in[6];
    float* out = (float*)d_out;

    hipFuncSetAttribute(reinterpret_cast<const void*>(k_gateup2),
                        hipFuncAttributeMaxDynamicSharedMemorySize, 131072);
    hipFuncSetAttribute(reinterpret_cast<const void*>(k_down2),
                        hipFuncAttributeMaxDynamicSharedMemorySize, 133120);

    const size_t NX = (size_t)NTOK * HID;
    const size_t PLANE = (size_t)INTER * HID * 2;     // bytes per expert per plane
    const size_t HB1   = (size_t)CAP * INTER * 2;

    char* wsb = (char*)d_ws;
    size_t off = 0;
    auto alloc = [&](size_t bytes) -> char* {
        char* r = wsb + off;
        off = (off + bytes + 255) & ~(size_t)255;
        return r;
    };
    float* counts = (float*)alloc((size_t)NTOK * 4);
    float* aux    = (float*)alloc(256);
    float* logits = (float*)alloc((size_t)NTOK * NEXP * 4);
    float* mxsum  = (float*)alloc(256);
    int*   tidx   = (int*)  alloc((size_t)NEXP * CAP * 4);
    float* tprob  = (float*)alloc((size_t)NEXP * CAP * 4);
    ushort_t* xhi = (ushort_t*)alloc(NX * 2);         // xlo contiguous after
    ushort_t* xlo = (ushort_t*)alloc(NX * 2);
    (void)xlo;

    // pick expert group size
    const size_t base_end = off;
    int G = 8;
    while (G > 1 && base_end + (size_t)G * (6 * PLANE + HB1) + 8192 > ws_size) G >>= 1;

    ushort_t* wghi = (ushort_t*)alloc((size_t)G * PLANE);   // wglo follows
    ushort_t* wglo = (ushort_t*)alloc((size_t)G * PLANE);
    ushort_t* wuhi = (ushort_t*)alloc((size_t)G * PLANE);
    ushort_t* wulo = (ushort_t*)alloc((size_t)G * PLANE);
    ushort_t* wdhi = (ushort_t*)alloc((size_t)G * PLANE);
    ushort_t* wdlo = (ushort_t*)alloc((size_t)G * PLANE);
    ushort_t* hbuf = (ushort_t*)alloc((size_t)G * HB1);
    (void)wglo; (void)wulo; (void)wdlo;

    hipMemsetAsync(d_out, 0, NX * 4 + 4, stream);
    hipMemsetAsync(counts, 0, (size_t)NTOK * 4 + 256, stream);

    k_ln_split_router<<<512, 256, 0, stream>>>(x, gamma, beta, gw, xhi, xlo, logits, aux);
    k_colmaxsum<<<NEXP, 256, 0, stream>>>(logits, mxsum);
    k_topk<<<NEXP, 1024, 0, stream>>>(logits, mxsum, tidx, tprob, counts);

    const int n4g = (int)((size_t)G * INTER * HID / 4);
    for (int gb = 0; gb < NEXP; gb += G) {
        const size_t woff = (size_t)gb * INTER * HID;
        k_split<<<2048, 256, 0, stream>>>(wg + woff, wghi, wglo, n4g);
        k_split<<<2048, 256, 0, stream>>>(wu + woff, wuhi, wulo, n4g);
        k_split<<<2048, 256, 0, stream>>>(wd + woff, wdhi, wdlo, n4g);

        k_gateup2<<<dim3(INTER / 128, CAP / 256, G), 512, 131072, stream>>>(
            xhi, wghi, wuhi, tidx, hbuf, gb, G);
        k_down2<<<dim3(HID / 128, CAP / 256, G), 512, 133120, stream>>>(
            hbuf, wdhi, tidx, tprob, out, gb, G);
    }

    k_final<<<(NTOK * HID / 4) / 256, 256, 0, stream>>>(out, counts, aux);
}